// Round 7
// baseline (858.451 us; speedup 1.0000x reference)
//
#include <hip/hip_runtime.h>

typedef float f32x4 __attribute__((ext_vector_type(4)));
typedef short s16x8 __attribute__((ext_vector_type(8)));
typedef unsigned int u32;
typedef unsigned long long u64;

// ---------------- problem constants ----------------
#define B_    32
#define T_    64
#define TCAP_ 63
#define V_    32000
#define IMGD_ 20480
#define E_    512
#define H_    500
#define KP_   512      // padded K for MFMA

// ---------------- ws layout (bytes) ----------------
#define OFF_XZ     0ul          // xz [64][32][2000] f32 (16,384,000)
#define OFF_XB     16384000ul   // xb [2048][512] bf16, row m = b*64+t
#define OFF_WLT    18481152ul   // wlt [2048][512] bf16 (W_lstm^T, n-major, padded)
#define OFF_HPAD   20578304ul   // hpad [2][32][512] bf16 (double-buffered h state)
#define OFF_HS     20643840ul   // hs [32][64][512] bf16
#define OFF_UPREP  22740992ul   // uprep [32 wg][64 c][512 k] bf16
#define OFF_WT     24838144ul   // wt [32000][512] bf16 (W_out^T, K-padded)
#define OFF_RS     57606144ul   // rowsum [2048] f32

// d_out scratch (overwritten by k_gemm<1> at the end):
//   flags: d_out[0..32)  (u32, per-WG scan flags, zeroed by k_prep each call)
//   x32  : d_out+1024    (f32 [32][512] image-embed accumulator)

__device__ __forceinline__ short bf16rn(float f) {
  u32 u = __float_as_uint(f);
  u += 0x7fff + ((u >> 16) & 1);
  return (short)(u >> 16);
}
__device__ __forceinline__ float sigf(float x) {
  return 1.0f / (1.0f + __expf(-x));
}
__device__ __forceinline__ void gload_lds16(const void* g, void* l) {
  __builtin_amdgcn_global_load_lds((const __attribute__((address_space(1))) void*)g,
                                   (__attribute__((address_space(3))) void*)l, 16, 0, 0);
}

// ---------------- fused prep ----------------
// SEG0 xb caption rows [0,504) | SEG1 x32 init [504,520) | SEG2 rowsum [520,522)
// SEG3 flags [522,523) | SEG4 uprep [523,4619) | SEG5 wt [4619,12619)
// SEG6 wlt [12619,13131)
#define SG_XB   504
#define SG_X32  520
#define SG_RS   522
#define SG_FL   523
#define SG_UP   4619
#define SG_WT   12619
#define SG_WLT  13131
__global__ __launch_bounds__(256) void k_prep(const float* __restrict__ bimg,
                                              const float* __restrict__ emb,
                                              const int* __restrict__ cap,
                                              const float* __restrict__ U,
                                              const float* __restrict__ Wo,
                                              const float* __restrict__ Wl,
                                              short* __restrict__ xb,
                                              float* __restrict__ x32,
                                              float* __restrict__ rowsum,
                                              u32* __restrict__ flags,
                                              short* __restrict__ up,
                                              short* __restrict__ wt,
                                              short* __restrict__ wlt) {
  __shared__ float s[32][65];
  int bid = blockIdx.x, tid = threadIdx.x;
  if (bid < SG_XB) {                     // xb rows t=1..63 from embedding gather
    int u = bid * 256 + tid;             // [0, 129024)
    int r = u >> 6, j8 = u & 63;
    int b = r / 63, tt = r - b * 63;
    int e = cap[b * TCAP_ + tt];
    const float* src = emb + (size_t)e * E_ + j8 * 8;
    f32x4 v0 = *(const f32x4*)src;
    f32x4 v1 = *(const f32x4*)(src + 4);
    s16x8 o;
    o[0]=bf16rn(v0.x); o[1]=bf16rn(v0.y); o[2]=bf16rn(v0.z); o[3]=bf16rn(v0.w);
    o[4]=bf16rn(v1.x); o[5]=bf16rn(v1.y); o[6]=bf16rn(v1.z); o[7]=bf16rn(v1.w);
    *(s16x8*)(xb + (size_t)(b * T_ + tt + 1) * KP_ + j8 * 8) = o;
  } else if (bid < SG_X32) {             // x32 init with bias
    int i = (bid - SG_XB) * 256 + tid;   // [0,4096)
    int b = i >> 7, j = i & 127;
    *(f32x4*)(x32 + b * E_ + j * 4) = *(const f32x4*)(bimg + j * 4);
  } else if (bid < SG_RS) {              // rowsum zero
    int i = (bid - SG_X32) * 256 + tid;  // [0,512)
    *(f32x4*)(rowsum + i * 4) = (f32x4){0.f, 0.f, 0.f, 0.f};
  } else if (bid < SG_FL) {              // flags zero (graph-replay reset)
    if (tid < 32) flags[tid] = 0u;
  } else if (bid < SG_UP) {              // uprep [wg][c][k]
    int idx = (bid - SG_FL) * 256 + tid; // [0, 1048576)
    int k = idx & 511;
    int c = (idx >> 9) & 63;
    int wg = idx >> 15;
    int q = c >> 4, dl = c & 15, dg = wg * 16 + dl;
    float v = 0.f;
    if (dg < H_ && k < H_) v = U[(size_t)k * 2000 + q * H_ + dg];
    up[idx] = bf16rn(v);
  } else if (bid < SG_WT) {              // wt = W_out^T bf16, K-padded
    int r = bid - SG_UP;
    int nt = r % 500, kt = r / 500;
    int n0 = nt * 64, k0 = kt * 32;
    for (int u = tid; u < 2048; u += 256) {
      int kl = u >> 6, nl = u & 63;
      int k = k0 + kl;
      s[kl][nl] = (k < H_) ? Wo[(size_t)k * V_ + n0 + nl] : 0.f;
    }
    __syncthreads();
    for (int u = tid; u < 2048; u += 256) {
      int nl = u >> 5, kl = u & 31;
      wt[(size_t)(n0 + nl) * KP_ + k0 + kl] = bf16rn(s[kl][nl]);
    }
  } else {                               // wlt = W_lstm^T bf16, n-padded to 2048
    int r = bid - SG_WT;
    int nt = r & 31, kt = r >> 5;
    int n0 = nt * 64, k0 = kt * 32;
    for (int u = tid; u < 2048; u += 256) {
      int kl = u >> 6, nl = u & 63;
      int n = n0 + nl;
      s[kl][nl] = (n < 2000) ? Wl[(size_t)(k0 + kl) * 2000 + n] : 0.f;
    }
    __syncthreads();
    for (int u = tid; u < 2048; u += 256) {
      int nl = u >> 5, kl = u & 31;
      wlt[(size_t)(n0 + nl) * KP_ + k0 + kl] = bf16rn(s[kl][nl]);
    }
  }
}

// ---------------- image-embed GEMM: atomicAdd into x32 (d_out scratch) ---------
__global__ __launch_bounds__(256) void k_img(const float* __restrict__ img,
                                             const float* __restrict__ W,
                                             float* __restrict__ x32) {
  __shared__ float simg[32][128];
  int ct = blockIdx.x & 7;
  int ks = blockIdx.x >> 3;
  int tid = threadIdx.x;
  int j = tid & 63, bq = tid >> 6;
  int col = ct * 64 + j;
  float acc[8] = {0.f, 0.f, 0.f, 0.f, 0.f, 0.f, 0.f, 0.f};
  int kbeg = ks * 1280;
  for (int k0 = kbeg; k0 < kbeg + 1280; k0 += 128) {
    __syncthreads();
    for (int u = tid; u < 32 * 32; u += 256) {
      int b = u >> 5, kq = (u & 31) * 4;
      *(f32x4*)&simg[b][kq] = *(const f32x4*)(img + (size_t)b * IMGD_ + k0 + kq);
    }
    __syncthreads();
    for (int k = 0; k < 128; ++k) {
      float w = W[(size_t)(k0 + k) * E_ + col];
#pragma unroll
      for (int r = 0; r < 8; ++r) acc[r] += simg[bq * 8 + r][k] * w;
    }
  }
#pragma unroll
  for (int r = 0; r < 8; ++r)
    atomicAdd(x32 + (bq * 8 + r) * E_ + col, acc[r]);
}

// ---------------- xb t=0 rows: convert x32 f32 -> bf16 -------------------------
__global__ __launch_bounds__(256) void k_xb(const float* __restrict__ x32,
                                            short* __restrict__ xb) {
  int u = blockIdx.x * 256 + threadIdx.x;   // [0,2048)
  int b = u >> 6, j8 = u & 63;
  const float* src = x32 + b * E_ + j8 * 8;
  f32x4 v0 = *(const f32x4*)src;
  f32x4 v1 = *(const f32x4*)(src + 4);
  s16x8 o;
  o[0]=bf16rn(v0.x); o[1]=bf16rn(v0.y); o[2]=bf16rn(v0.z); o[3]=bf16rn(v0.w);
  o[4]=bf16rn(v1.x); o[5]=bf16rn(v1.y); o[6]=bf16rn(v1.z); o[7]=bf16rn(v1.w);
  *(s16x8*)(xb + (size_t)(b * T_) * KP_ + j8 * 8) = o;
}

// ---------------- xz GEMM (bf16 MFMA): xz[t][b][n] = xb @ wlt^T + bl -----------
__global__ __launch_bounds__(256) void k_xzm(const short* __restrict__ A,
                                             const short* __restrict__ Bt,
                                             const float* __restrict__ bl,
                                             float* __restrict__ xz) {
  __shared__ short sA[2][128 * 64];
  __shared__ short sB[2][128 * 64];
  int bid = blockIdx.x;
  int mt = bid & 15, nt = bid >> 4;
  int m0 = mt * 128, n0 = nt * 128;
  int tid = threadIdx.x;
  int lane = tid & 63, w = tid >> 6;
  int wr = w >> 1, wc = w & 1;
  int l15 = lane & 15, l4 = lane >> 4;

  f32x4 acc[4][4];
#pragma unroll
  for (int i = 0; i < 4; ++i)
#pragma unroll
    for (int j = 0; j < 4; ++j) acc[i][j] = (f32x4){0.f, 0.f, 0.f, 0.f};

  auto stage = [&](int kc, int buf) {
    const short* ga = A + (size_t)m0 * KP_ + kc * 64;
    const short* gb = Bt + (size_t)n0 * KP_ + kc * 64;
#pragma unroll
    for (int i = 0; i < 4; ++i) {
      int ch = tid + i * 256;
      int rr = ch >> 3, kq = (ch & 7) * 8;
      gload_lds16(ga + (size_t)rr * KP_ + kq, &sA[buf][rr * 64 + kq]);
      gload_lds16(gb + (size_t)rr * KP_ + kq, &sB[buf][rr * 64 + kq]);
    }
  };

  stage(0, 0);
  __syncthreads();
  int buf = 0;
  for (int kc = 0; kc < 8; ++kc) {
    if (kc < 7) stage(kc + 1, buf ^ 1);
#pragma unroll
    for (int k2 = 0; k2 < 2; ++k2) {
      int kloc = k2 * 32 + l4 * 8;
      s16x8 af[4], bfr[4];
#pragma unroll
      for (int fm = 0; fm < 4; ++fm)
        af[fm] = *(const s16x8*)&sA[buf][(wr * 64 + fm * 16 + l15) * 64 + kloc];
#pragma unroll
      for (int fn = 0; fn < 4; ++fn)
        bfr[fn] = *(const s16x8*)&sB[buf][(wc * 64 + fn * 16 + l15) * 64 + kloc];
#pragma unroll
      for (int fm = 0; fm < 4; ++fm)
#pragma unroll
        for (int fn = 0; fn < 4; ++fn)
          acc[fm][fn] = __builtin_amdgcn_mfma_f32_16x16x32_bf16(af[fm], bfr[fn], acc[fm][fn], 0, 0, 0);
    }
    __syncthreads();
    buf ^= 1;
  }

  float bln[4];
#pragma unroll
  for (int fn = 0; fn < 4; ++fn) {
    int n = n0 + wc * 64 + fn * 16 + l15;
    bln[fn] = (n < 2000) ? bl[n] : 0.f;
  }
#pragma unroll
  for (int fm = 0; fm < 4; ++fm) {
#pragma unroll
    for (int reg = 0; reg < 4; ++reg) {
      int m = m0 + wr * 64 + fm * 16 + l4 * 4 + reg;
      int b = m >> 6, t = m & 63;
#pragma unroll
      for (int fn = 0; fn < 4; ++fn) {
        int n = n0 + wc * 64 + fn * 16 + l15;
        if (n < 2000)
          xz[((size_t)t * B_ + b) * 2000 + n] = acc[fm][fn][reg] + bln[fn];
      }
    }
  }
}

// ---------------- LSTM scan: cooperative, 32 WGs x 128 thr (R3-proven) ---------
// Fence-free device coherence: h exchanged via relaxed AGENT-scope atomics
// (sc1 write-through stores to MALL, sc1 bypass loads from MALL).
// __syncthreads() drains vmcnt so the flag store is ordered after the h stores.
// t=0 skips the h@U MFMA (h==0), so hpad needs no zero-init.
__global__ __launch_bounds__(128) void k_scan(const short* __restrict__ up,
                                              const float* __restrict__ xz,
                                              short* hpad,
                                              short* __restrict__ hs,
                                              u32* flags) {
  __shared__ short Ul[64 * 512];  // XOR-swizzled [c][k] bf16
  int wg = blockIdx.x;
  int tid = threadIdx.x;
  int lane = tid & 63, mtile = tid >> 6;
  int dl = lane & 15, g16 = lane >> 4;

  // stage U slice (swizzled to kill the 16-way ds_read_b128 bank conflict)
  const short* usrc = up + (size_t)wg * 64 * 512;
  for (int u = tid; u < 4096; u += 128) {
    int c = u >> 6, kq = (u & 63) * 8;
    u32 off = ((u32)(c * 512 + kq) * 2) ^ ((u32)(c & 7) << 4);
    *(s16x8*)((char*)Ul + off) = *(const s16x8*)(usrc + c * 512 + kq);
  }
  __syncthreads();

  int dg = wg * 16 + dl;
  bool dvalid = dg < H_;
  float cst[4] = {0.f, 0.f, 0.f, 0.f};
  int brow = mtile * 16 + dl;  // A-frag row (= batch index)

  float xzr[4][4];
  auto pf = [&](int t) {
#pragma unroll
    for (int q = 0; q < 4; ++q)
#pragma unroll
      for (int reg = 0; reg < 4; ++reg) {
        int b = mtile * 16 + g16 * 4 + reg;
        xzr[q][reg] = dvalid ? xz[((size_t)t * B_ + b) * 2000 + q * 500 + dg] : 0.f;
      }
  };
  pf(0);

  for (int t = 0; t < 64; ++t) {
    f32x4 acc[4];
#pragma unroll
    for (int q = 0; q < 4; ++q) acc[q] = (f32x4){0.f, 0.f, 0.f, 0.f};

    if (t > 0) {
      const short* hsrc = hpad + (size_t)(t & 1) * (B_ * KP_);
      u64 q0[16], q1[16];
#pragma unroll
      for (int kk = 0; kk < 16; ++kk) {
        const u64* p = (const u64*)(hsrc + brow * KP_ + kk * 32 + g16 * 8);
        q0[kk] = __hip_atomic_load(p,     __ATOMIC_RELAXED, __HIP_MEMORY_SCOPE_AGENT);
        q1[kk] = __hip_atomic_load(p + 1, __ATOMIC_RELAXED, __HIP_MEMORY_SCOPE_AGENT);
      }
#pragma unroll
      for (int kk = 0; kk < 16; ++kk) {
        union { s16x8 v; u64 q[2]; } fr;
        fr.q[0] = q0[kk]; fr.q[1] = q1[kk];
#pragma unroll
        for (int q = 0; q < 4; ++q) {
          int c = q * 16 + dl;
          u32 off = ((u32)(c * 512 + kk * 32 + g16 * 8) * 2) ^ ((u32)(c & 7) << 4);
          s16x8 bfr = *(const s16x8*)((const char*)Ul + off);
          acc[q] = __builtin_amdgcn_mfma_f32_16x16x32_bf16(fr.v, bfr, acc[q], 0, 0, 0);
        }
      }
    }

    short hb4[4];
#pragma unroll
    for (int reg = 0; reg < 4; ++reg) {
      float zi = acc[0][reg] + xzr[0][reg];
      float zf = acc[1][reg] + xzr[1][reg];
      float zc = acc[2][reg] + xzr[2][reg];
      float zo = acc[3][reg] + xzr[3][reg];
      float ig = sigf(zi), fg = sigf(zf), gt = tanhf(zc), og = sigf(zo);
      float cn = fg * cst[reg] + ig * gt;
      cst[reg] = cn;
      float h = og * tanhf(cn);
      if (!dvalid) h = 0.f;
      hb4[reg] = bf16rn(h);
    }

    // pack h pairs (dg, dg^1) via shuffle -> one u32 agent-scope store each
    short* hnext = hpad + (size_t)((t + 1) & 1) * (B_ * KP_);
#pragma unroll
    for (int reg = 0; reg < 4; ++reg) {
      int mine = (int)(u32)(unsigned short)hb4[reg];
      int oth = __shfl_xor(mine, 1);
      if ((dl & 1) == 0) {
        int b = mtile * 16 + g16 * 4 + reg;
        u32 val = ((u32)mine) | ((u32)oth << 16);
        __hip_atomic_store((u32*)hnext + ((b * KP_ + dg) >> 1), val,
                           __ATOMIC_RELAXED, __HIP_MEMORY_SCOPE_AGENT);
      }
    }

    if (t < 63) {
      __syncthreads();   // vmcnt(0) drain: h stores acked at MALL before flag
      if (tid == 0)
        __hip_atomic_store(&flags[wg], (u32)(t + 1),
                           __ATOMIC_RELAXED, __HIP_MEMORY_SCOPE_AGENT);
      asm volatile("" ::: "memory");
      // overlapped with the barrier wait: hs stores + next-step xz prefetch
#pragma unroll
      for (int reg = 0; reg < 4; ++reg) {
        int b = mtile * 16 + g16 * 4 + reg;
        hs[((size_t)b * T_ + t) * KP_ + dg] = hb4[reg];
      }
      pf(t + 1);
      if (tid < 64) {
        u32 target = (u32)(t + 1);
        int slot = tid & 31;
        while (true) {
          u32 v = __hip_atomic_load(&flags[slot], __ATOMIC_RELAXED,
                                    __HIP_MEMORY_SCOPE_AGENT);
          if (__all(v >= target)) break;
          __builtin_amdgcn_s_sleep(1);
        }
      }
      __syncthreads();
    } else {
#pragma unroll
      for (int reg = 0; reg < 4; ++reg) {
        int b = mtile * 16 + g16 * 4 + reg;
        hs[((size_t)b * T_ + t) * KP_ + dg] = hb4[reg];
      }
    }
  }
}

// ---------------- logits GEMM, two phases, A direct-from-L2 -------------------
// A (hs, 2MB bf16) is fully L2-resident: read fragments directly from global
// (lanes l4=0..3 cover 64B contiguous). Only B staged in LDS (32KB total)
// -> 5 blocks/CU. PHASE 0: exp + per-row atomic sums (no out write).
// PHASE 1: deterministic recompute, writes p = e / rowsum. Replaces k_norm.
// grid 4000 = 16 m-tiles x 250 n-tiles, 256 thr (4 waves, 64x64 quadrants)
template <int PHASE>
__global__ __launch_bounds__(256) void k_gemm(const short* __restrict__ A,
                                              const short* __restrict__ Bt,
                                              const float* __restrict__ bout,
                                              float* __restrict__ out,
                                              float* __restrict__ rowsum) {
  __shared__ short sB[2][128 * 64];
  int bid = blockIdx.x;
  int mt = bid & 15, nt = bid >> 4;
  int m0 = mt * 128, n0 = nt * 128;
  int tid = threadIdx.x;
  int lane = tid & 63, w = tid >> 6;
  int wr = w >> 1, wc = w & 1;
  int l15 = lane & 15, l4 = lane >> 4;

  f32x4 acc[4][4];
#pragma unroll
  for (int i = 0; i < 4; ++i)
#pragma unroll
    for (int j = 0; j < 4; ++j) acc[i][j] = (f32x4){0.f, 0.f, 0.f, 0.f};

  // per-fm A row base (global, L2-hot)
  const short* arow[4];
#pragma unroll
  for (int fm = 0; fm < 4; ++fm)
    arow[fm] = A + (size_t)(m0 + wr * 64 + fm * 16 + l15) * KP_ + l4 * 8;

  auto stage = [&](int kc, int buf) {
    const short* gb = Bt + (size_t)n0 * KP_ + kc * 64;
#pragma unroll
    for (int i = 0; i < 4; ++i) {
      int ch = tid + i * 256;
      int rr = ch >> 3, kq = (ch & 7) * 8;
      gload_lds16(gb + (size_t)rr * KP_ + kq, &sB[buf][rr * 64 + kq]);
    }
  };

  stage(0, 0);
  __syncthreads();
  int buf = 0;
  for (int kc = 0; kc < 8; ++kc) {
    if (kc < 7) stage(kc + 1, buf ^ 1);
#pragma unroll
    for (int k2 = 0; k2 < 2; ++k2) {
      int kloc = k2 * 32 + l4 * 8;
      s16x8 af[4], bfr[4];
#pragma unroll
      for (int fm = 0; fm < 4; ++fm)
        af[fm] = *(const s16x8*)(arow[fm] + kc * 64 + k2 * 32);
#pragma unroll
      for (int fn = 0; fn < 4; ++fn)
        bfr[fn] = *(const s16x8*)&sB[buf][(wc * 64 + fn * 16 + l15) * 64 + kloc];
#pragma unroll
      for (int fm = 0; fm < 4; ++fm)
#pragma unroll
        for (int fn = 0; fn < 4; ++fn)
          acc[fm][fn] = __builtin_amdgcn_mfma_f32_16x16x32_bf16(af[fm], bfr[fn], acc[fm][fn], 0, 0, 0);
    }
    __syncthreads();
    buf ^= 1;
  }

  float bo4[4];
#pragma unroll
  for (int fn = 0; fn < 4; ++fn) bo4[fn] = bout[n0 + wc * 64 + fn * 16 + l15];

#pragma unroll
  for (int fm = 0; fm < 4; ++fm) {
#pragma unroll
    for (int reg = 0; reg < 4; ++reg) {
      int m = m0 + wr * 64 + fm * 16 + l4 * 4 + reg;
      if constexpr (PHASE == 0) {
        float s = 0.f;
#pragma unroll
        for (int fn = 0; fn < 4; ++fn)
          s += __expf(acc[fm][fn][reg] + bo4[fn]);
        s += __shfl_xor(s, 1);
        s += __shfl_xor(s, 2);
        s += __shfl_xor(s, 4);
        s += __shfl_xor(s, 8);
        if (l15 == 0) atomicAdd(&rowsum[m], s);
      } else {
        float inv = 1.0f / rowsum[m];
#pragma unroll
        for (int fn = 0; fn < 4; ++fn) {
          int n = n0 + wc * 64 + fn * 16 + l15;
          float e = __expf(acc[fm][fn][reg] + bo4[fn]);
          out[(size_t)m * V_ + n] = e * inv;
        }
      }
    }
  }
}

extern "C" void kernel_launch(void* const* d_in, const int* in_sizes, int n_in,
                              void* d_out, int out_size, void* d_ws, size_t ws_size,
                              hipStream_t stream) {
  const float* img  = (const float*)d_in[0];
  const int*   cap  = (const int*)  d_in[1];
  const float* Wimg = (const float*)d_in[2];
  const float* bimg = (const float*)d_in[3];
  const float* emb  = (const float*)d_in[4];
  const float* Wl   = (const float*)d_in[5];
  const float* Ulm  = (const float*)d_in[6];
  const float* bl   = (const float*)d_in[7];
  const float* Wo   = (const float*)d_in[8];
  const float* bo   = (const float*)d_in[9];
  float* out = (float*)d_out;
  char* ws = (char*)d_ws;

  float* xz     = (float*)(ws + OFF_XZ);
  short* xb     = (short*)(ws + OFF_XB);
  short* wlt    = (short*)(ws + OFF_WLT);
  short* hpad   = (short*)(ws + OFF_HPAD);
  short* hs     = (short*)(ws + OFF_HS);
  short* uprep  = (short*)(ws + OFF_UPREP);
  short* wt     = (short*)(ws + OFF_WT);
  float* rowsum = (float*)(ws + OFF_RS);
  u32*   flags  = (u32*)d_out;               // d_out[0..32), zeroed by k_prep
  float* x32    = (float*)d_out + 1024;      // d_out scratch, overwritten later

  k_prep<<<SG_WLT, 256, 0, stream>>>(bimg, emb, cap, Ulm, Wo, Wl,
                                     xb, x32, rowsum, flags, uprep, wt, wlt);
  k_img<<<128, 256, 0, stream>>>(img, Wimg, x32);
  k_xb<<<8, 256, 0, stream>>>(x32, xb);
  k_xzm<<<256, 256, 0, stream>>>(xb, wlt, bl, xz);

  {
    const short* up_p = uprep;
    const float* xz_p = xz;
    short* hpad_p = hpad;
    short* hs_p = hs;
    u32* flags_p = flags;
    void* args[] = {&up_p, &xz_p, &hpad_p, &hs_p, &flags_p};
    hipLaunchCooperativeKernel((void*)k_scan, dim3(32), dim3(128), args, 0, stream);
  }

  k_gemm<0><<<4000, 256, 0, stream>>>(hs, wt, bo, out, rowsum);
  k_gemm<1><<<4000, 256, 0, stream>>>(hs, wt, bo, out, rowsum);
}

// Round 9
// 768.482 us; speedup vs baseline: 1.1171x; 1.1171x over previous
//
#include <hip/hip_runtime.h>

typedef float f32x4 __attribute__((ext_vector_type(4)));
typedef short s16x8 __attribute__((ext_vector_type(8)));
typedef unsigned int u32;
typedef unsigned long long u64;

// ---------------- problem constants ----------------
#define B_    32
#define T_    64
#define TCAP_ 63
#define V_    32000
#define IMGD_ 20480
#define E_    512
#define H_    500
#define KP_   512      // padded K for MFMA

// ---------------- ws layout (bytes) ----------------
#define OFF_XZ     0ul          // xz [64][32][2000] f32 (16,384,000)
#define OFF_XB     16384000ul   // xb [2048][512] bf16, row m = b*64+t
#define OFF_WLT    18481152ul   // wlt [2048][512] bf16 (W_lstm^T, n-major, padded)
#define OFF_HPAD   20578304ul   // hpad [2][32][512] bf16 (double-buffered h state)
#define OFF_HS     20643840ul   // hs [32][64][512] bf16
#define OFF_UPREP  22740992ul   // uprep [32 wg][64 c][512 k] bf16
#define OFF_WT     24838144ul   // wt [32000][512] bf16 (W_out^T, K-padded)
#define OFF_RS     57606144ul   // rowsum [2048] f32

// d_out scratch (overwritten by k_gemm/k_norm at the end):
//   flags: d_out[0..32)  (u32, per-WG scan flags, zeroed by k_prep each call)
//   x32  : d_out+1024    (f32 [32][512] image-embed accumulator)

__device__ __forceinline__ short bf16rn(float f) {
  u32 u = __float_as_uint(f);
  u += 0x7fff + ((u >> 16) & 1);
  return (short)(u >> 16);
}
__device__ __forceinline__ float sigf(float x) {
  return 1.0f / (1.0f + __expf(-x));
}
__device__ __forceinline__ void gload_lds16(const void* g, void* l) {
  __builtin_amdgcn_global_load_lds((const __attribute__((address_space(1))) void*)g,
                                   (__attribute__((address_space(3))) void*)l, 16, 0, 0);
}

// ---------------- fused prep (wt moved into the cooperative kernel) ------------
// SEG0 xb caption rows [0,504) | SEG1 x32 init [504,520) | SEG2 rowsum [520,522)
// SEG3 flags [522,523) | SEG4 uprep [523,4619) | SEG5 wlt [4619,5131)
#define SG_XB   504
#define SG_X32  520
#define SG_RS   522
#define SG_FL   523
#define SG_UP   4619
#define SG_WLT  5131
__global__ __launch_bounds__(256) void k_prep(const float* __restrict__ bimg,
                                              const float* __restrict__ emb,
                                              const int* __restrict__ cap,
                                              const float* __restrict__ U,
                                              const float* __restrict__ Wl,
                                              short* __restrict__ xb,
                                              float* __restrict__ x32,
                                              float* __restrict__ rowsum,
                                              u32* __restrict__ flags,
                                              short* __restrict__ up,
                                              short* __restrict__ wlt) {
  __shared__ float s[32][65];
  int bid = blockIdx.x, tid = threadIdx.x;
  if (bid < SG_XB) {                     // xb rows t=1..63 from embedding gather
    int u = bid * 256 + tid;             // [0, 129024)
    int r = u >> 6, j8 = u & 63;
    int b = r / 63, tt = r - b * 63;
    int e = cap[b * TCAP_ + tt];
    const float* src = emb + (size_t)e * E_ + j8 * 8;
    f32x4 v0 = *(const f32x4*)src;
    f32x4 v1 = *(const f32x4*)(src + 4);
    s16x8 o;
    o[0]=bf16rn(v0.x); o[1]=bf16rn(v0.y); o[2]=bf16rn(v0.z); o[3]=bf16rn(v0.w);
    o[4]=bf16rn(v1.x); o[5]=bf16rn(v1.y); o[6]=bf16rn(v1.z); o[7]=bf16rn(v1.w);
    *(s16x8*)(xb + (size_t)(b * T_ + tt + 1) * KP_ + j8 * 8) = o;
  } else if (bid < SG_X32) {             // x32 init with bias
    int i = (bid - SG_XB) * 256 + tid;   // [0,4096)
    int b = i >> 7, j = i & 127;
    *(f32x4*)(x32 + b * E_ + j * 4) = *(const f32x4*)(bimg + j * 4);
  } else if (bid < SG_RS) {              // rowsum zero
    int i = (bid - SG_X32) * 256 + tid;  // [0,512)
    *(f32x4*)(rowsum + i * 4) = (f32x4){0.f, 0.f, 0.f, 0.f};
  } else if (bid < SG_FL) {              // flags zero (graph-replay reset)
    if (tid < 32) flags[tid] = 0u;
  } else if (bid < SG_UP) {              // uprep [wg][c][k]
    int idx = (bid - SG_FL) * 256 + tid; // [0, 1048576)
    int k = idx & 511;
    int c = (idx >> 9) & 63;
    int wg = idx >> 15;
    int q = c >> 4, dl = c & 15, dg = wg * 16 + dl;
    float v = 0.f;
    if (dg < H_ && k < H_) v = U[(size_t)k * 2000 + q * H_ + dg];
    up[idx] = bf16rn(v);
  } else {                               // wlt = W_lstm^T bf16, n-padded to 2048
    int r = bid - SG_UP;
    int nt = r & 31, kt = r >> 5;
    int n0 = nt * 64, k0 = kt * 32;
    for (int u = tid; u < 2048; u += 256) {
      int kl = u >> 6, nl = u & 63;
      int n = n0 + nl;
      s[kl][nl] = (n < 2000) ? Wl[(size_t)(k0 + kl) * 2000 + n] : 0.f;
    }
    __syncthreads();
    for (int u = tid; u < 2048; u += 256) {
      int nl = u >> 5, kl = u & 31;
      wlt[(size_t)(n0 + nl) * KP_ + k0 + kl] = bf16rn(s[kl][nl]);
    }
  }
}

// ---------------- image-embed GEMM: atomicAdd into x32 (d_out scratch) ---------
__global__ __launch_bounds__(256) void k_img(const float* __restrict__ img,
                                             const float* __restrict__ W,
                                             float* __restrict__ x32) {
  __shared__ float simg[32][128];
  int ct = blockIdx.x & 7;
  int ks = blockIdx.x >> 3;
  int tid = threadIdx.x;
  int j = tid & 63, bq = tid >> 6;
  int col = ct * 64 + j;
  float acc[8] = {0.f, 0.f, 0.f, 0.f, 0.f, 0.f, 0.f, 0.f};
  int kbeg = ks * 1280;
  for (int k0 = kbeg; k0 < kbeg + 1280; k0 += 128) {
    __syncthreads();
    for (int u = tid; u < 32 * 32; u += 256) {
      int b = u >> 5, kq = (u & 31) * 4;
      *(f32x4*)&simg[b][kq] = *(const f32x4*)(img + (size_t)b * IMGD_ + k0 + kq);
    }
    __syncthreads();
    for (int k = 0; k < 128; ++k) {
      float w = W[(size_t)(k0 + k) * E_ + col];
#pragma unroll
      for (int r = 0; r < 8; ++r) acc[r] += simg[bq * 8 + r][k] * w;
    }
  }
#pragma unroll
  for (int r = 0; r < 8; ++r)
    atomicAdd(x32 + (bq * 8 + r) * E_ + col, acc[r]);
}

// ---------------- xb t=0 rows: convert x32 f32 -> bf16 -------------------------
__global__ __launch_bounds__(256) void k_xb(const float* __restrict__ x32,
                                            short* __restrict__ xb) {
  int u = blockIdx.x * 256 + threadIdx.x;   // [0,2048)
  int b = u >> 6, j8 = u & 63;
  const float* src = x32 + b * E_ + j8 * 8;
  f32x4 v0 = *(const f32x4*)src;
  f32x4 v1 = *(const f32x4*)(src + 4);
  s16x8 o;
  o[0]=bf16rn(v0.x); o[1]=bf16rn(v0.y); o[2]=bf16rn(v0.z); o[3]=bf16rn(v0.w);
  o[4]=bf16rn(v1.x); o[5]=bf16rn(v1.y); o[6]=bf16rn(v1.z); o[7]=bf16rn(v1.w);
  *(s16x8*)(xb + (size_t)(b * T_) * KP_ + j8 * 8) = o;
}

// ---------------- xz GEMM (bf16 MFMA): xz[t][b][n] = xb @ wlt^T + bl -----------
__global__ __launch_bounds__(256) void k_xzm(const short* __restrict__ A,
                                             const short* __restrict__ Bt,
                                             const float* __restrict__ bl,
                                             float* __restrict__ xz) {
  __shared__ short sA[2][128 * 64];
  __shared__ short sB[2][128 * 64];
  int bid = blockIdx.x;
  int mt = bid & 15, nt = bid >> 4;
  int m0 = mt * 128, n0 = nt * 128;
  int tid = threadIdx.x;
  int lane = tid & 63, w = tid >> 6;
  int wr = w >> 1, wc = w & 1;
  int l15 = lane & 15, l4 = lane >> 4;

  f32x4 acc[4][4];
#pragma unroll
  for (int i = 0; i < 4; ++i)
#pragma unroll
    for (int j = 0; j < 4; ++j) acc[i][j] = (f32x4){0.f, 0.f, 0.f, 0.f};

  auto stage = [&](int kc, int buf) {
    const short* ga = A + (size_t)m0 * KP_ + kc * 64;
    const short* gb = Bt + (size_t)n0 * KP_ + kc * 64;
#pragma unroll
    for (int i = 0; i < 4; ++i) {
      int ch = tid + i * 256;
      int rr = ch >> 3, kq = (ch & 7) * 8;
      gload_lds16(ga + (size_t)rr * KP_ + kq, &sA[buf][rr * 64 + kq]);
      gload_lds16(gb + (size_t)rr * KP_ + kq, &sB[buf][rr * 64 + kq]);
    }
  };

  stage(0, 0);
  __syncthreads();
  int buf = 0;
  for (int kc = 0; kc < 8; ++kc) {
    if (kc < 7) stage(kc + 1, buf ^ 1);
#pragma unroll
    for (int k2 = 0; k2 < 2; ++k2) {
      int kloc = k2 * 32 + l4 * 8;
      s16x8 af[4], bfr[4];
#pragma unroll
      for (int fm = 0; fm < 4; ++fm)
        af[fm] = *(const s16x8*)&sA[buf][(wr * 64 + fm * 16 + l15) * 64 + kloc];
#pragma unroll
      for (int fn = 0; fn < 4; ++fn)
        bfr[fn] = *(const s16x8*)&sB[buf][(wc * 64 + fn * 16 + l15) * 64 + kloc];
#pragma unroll
      for (int fm = 0; fm < 4; ++fm)
#pragma unroll
        for (int fn = 0; fn < 4; ++fn)
          acc[fm][fn] = __builtin_amdgcn_mfma_f32_16x16x32_bf16(af[fm], bfr[fn], acc[fm][fn], 0, 0, 0);
    }
    __syncthreads();
    buf ^= 1;
  }

  float bln[4];
#pragma unroll
  for (int fn = 0; fn < 4; ++fn) {
    int n = n0 + wc * 64 + fn * 16 + l15;
    bln[fn] = (n < 2000) ? bl[n] : 0.f;
  }
#pragma unroll
  for (int fm = 0; fm < 4; ++fm) {
#pragma unroll
    for (int reg = 0; reg < 4; ++reg) {
      int m = m0 + wr * 64 + fm * 16 + l4 * 4 + reg;
      int b = m >> 6, t = m & 63;
#pragma unroll
      for (int fn = 0; fn < 4; ++fn) {
        int n = n0 + wc * 64 + fn * 16 + l15;
        if (n < 2000)
          xz[((size_t)t * B_ + b) * 2000 + n] = acc[fm][fn][reg] + bln[fn];
      }
    }
  }
}

// ---------------- cooperative: LSTM scan (blocks 0..31) + wt workers (32..255) --
// Scan: R3/R6-proven flag protocol, verbatim. Workers: independent W_out^T->bf16
// transpose; no interaction with the flag barrier; wt consumed only after this
// kernel retires (stream order). Both paths share the 64KB static LDS.
__global__ __launch_bounds__(128) void k_scan(const short* __restrict__ up,
                                              const float* __restrict__ xz,
                                              short* hpad,
                                              short* __restrict__ hs,
                                              u32* flags,
                                              const float* __restrict__ Wo,
                                              short* __restrict__ wt) {
  __shared__ short Ul[64 * 512];  // scan: XOR-swizzled U; workers: f32 tile buf
  int wg = blockIdx.x;
  int tid = threadIdx.x;

  if (wg >= 32) {
    // -------- wt transpose worker: wt[n][k] = bf16(Wo[k][n]), K-padded --------
    float (*s)[65] = (float(*)[65])Ul;  // 32x65 f32 = 8320 B of the 64KB LDS
    for (int tile = wg - 32; tile < 8000; tile += 224) {
      int nt = tile % 500, kt = tile / 500;
      int n0 = nt * 64, k0 = kt * 32;
      __syncthreads();
      for (int u = tid; u < 2048; u += 128) {
        int kl = u >> 6, nl = u & 63;
        int k = k0 + kl;
        s[kl][nl] = (k < H_) ? Wo[(size_t)k * V_ + n0 + nl] : 0.f;
      }
      __syncthreads();
      for (int u = tid; u < 2048; u += 128) {
        int nl = u >> 5, kl = u & 31;
        wt[(size_t)(n0 + nl) * KP_ + k0 + kl] = bf16rn(s[kl][nl]);
      }
    }
    return;
  }

  int lane = tid & 63, mtile = tid >> 6;
  int dl = lane & 15, g16 = lane >> 4;

  // stage U slice (swizzled to kill the 16-way ds_read_b128 bank conflict)
  const short* usrc = up + (size_t)wg * 64 * 512;
  for (int u = tid; u < 4096; u += 128) {
    int c = u >> 6, kq = (u & 63) * 8;
    u32 off = ((u32)(c * 512 + kq) * 2) ^ ((u32)(c & 7) << 4);
    *(s16x8*)((char*)Ul + off) = *(const s16x8*)(usrc + c * 512 + kq);
  }
  __syncthreads();

  int dg = wg * 16 + dl;
  bool dvalid = dg < H_;
  float cst[4] = {0.f, 0.f, 0.f, 0.f};
  int brow = mtile * 16 + dl;  // A-frag row (= batch index)

  float xzr[4][4];
  auto pf = [&](int t) {
#pragma unroll
    for (int q = 0; q < 4; ++q)
#pragma unroll
      for (int reg = 0; reg < 4; ++reg) {
        int b = mtile * 16 + g16 * 4 + reg;
        xzr[q][reg] = dvalid ? xz[((size_t)t * B_ + b) * 2000 + q * 500 + dg] : 0.f;
      }
  };
  pf(0);

  for (int t = 0; t < 64; ++t) {
    f32x4 acc[4];
#pragma unroll
    for (int q = 0; q < 4; ++q) acc[q] = (f32x4){0.f, 0.f, 0.f, 0.f};

    if (t > 0) {
      const short* hsrc = hpad + (size_t)(t & 1) * (B_ * KP_);
      u64 q0[16], q1[16];
#pragma unroll
      for (int kk = 0; kk < 16; ++kk) {
        const u64* p = (const u64*)(hsrc + brow * KP_ + kk * 32 + g16 * 8);
        q0[kk] = __hip_atomic_load(p,     __ATOMIC_RELAXED, __HIP_MEMORY_SCOPE_AGENT);
        q1[kk] = __hip_atomic_load(p + 1, __ATOMIC_RELAXED, __HIP_MEMORY_SCOPE_AGENT);
      }
#pragma unroll
      for (int kk = 0; kk < 16; ++kk) {
        union { s16x8 v; u64 q[2]; } fr;
        fr.q[0] = q0[kk]; fr.q[1] = q1[kk];
#pragma unroll
        for (int q = 0; q < 4; ++q) {
          int c = q * 16 + dl;
          u32 off = ((u32)(c * 512 + kk * 32 + g16 * 8) * 2) ^ ((u32)(c & 7) << 4);
          s16x8 bfr = *(const s16x8*)((const char*)Ul + off);
          acc[q] = __builtin_amdgcn_mfma_f32_16x16x32_bf16(fr.v, bfr, acc[q], 0, 0, 0);
        }
      }
    }

    short hb4[4];
#pragma unroll
    for (int reg = 0; reg < 4; ++reg) {
      float zi = acc[0][reg] + xzr[0][reg];
      float zf = acc[1][reg] + xzr[1][reg];
      float zc = acc[2][reg] + xzr[2][reg];
      float zo = acc[3][reg] + xzr[3][reg];
      float ig = sigf(zi), fg = sigf(zf), gt = tanhf(zc), og = sigf(zo);
      float cn = fg * cst[reg] + ig * gt;
      cst[reg] = cn;
      float h = og * tanhf(cn);
      if (!dvalid) h = 0.f;
      hb4[reg] = bf16rn(h);
    }

    // pack h pairs (dg, dg^1) via shuffle -> one u32 agent-scope store each
    short* hnext = hpad + (size_t)((t + 1) & 1) * (B_ * KP_);
#pragma unroll
    for (int reg = 0; reg < 4; ++reg) {
      int mine = (int)(u32)(unsigned short)hb4[reg];
      int oth = __shfl_xor(mine, 1);
      if ((dl & 1) == 0) {
        int b = mtile * 16 + g16 * 4 + reg;
        u32 val = ((u32)mine) | ((u32)oth << 16);
        __hip_atomic_store((u32*)hnext + ((b * KP_ + dg) >> 1), val,
                           __ATOMIC_RELAXED, __HIP_MEMORY_SCOPE_AGENT);
      }
    }

    if (t < 63) {
      __syncthreads();   // vmcnt(0) drain: h stores acked at MALL before flag
      if (tid == 0)
        __hip_atomic_store(&flags[wg], (u32)(t + 1),
                           __ATOMIC_RELAXED, __HIP_MEMORY_SCOPE_AGENT);
      asm volatile("" ::: "memory");
      // overlapped with the barrier wait: hs stores + next-step xz prefetch
#pragma unroll
      for (int reg = 0; reg < 4; ++reg) {
        int b = mtile * 16 + g16 * 4 + reg;
        hs[((size_t)b * T_ + t) * KP_ + dg] = hb4[reg];
      }
      pf(t + 1);
      if (tid < 64) {
        u32 target = (u32)(t + 1);
        int slot = tid & 31;
        while (true) {
          u32 v = __hip_atomic_load(&flags[slot], __ATOMIC_RELAXED,
                                    __HIP_MEMORY_SCOPE_AGENT);
          if (__all(v >= target)) break;
          __builtin_amdgcn_s_sleep(1);
        }
      }
      __syncthreads();
    } else {
#pragma unroll
      for (int reg = 0; reg < 4; ++reg) {
        int b = mtile * 16 + g16 * 4 + reg;
        hs[((size_t)b * T_ + t) * KP_ + dg] = hb4[reg];
      }
    }
  }
}

// ---------------- logits GEMM (single pass, A direct-from-L2) + exp + sums -----
// A (hs, 2MB bf16) is L2-resident: fragments read directly from global.
// Only B staged in LDS (32KB) -> higher occupancy. Writes e, atomicAdds rowsum.
__global__ __launch_bounds__(256) void k_gemm(const short* __restrict__ A,
                                              const short* __restrict__ Bt,
                                              const float* __restrict__ bout,
                                              float* __restrict__ out,
                                              float* __restrict__ rowsum) {
  __shared__ short sB[2][128 * 64];
  int bid = blockIdx.x;
  int mt = bid & 15, nt = bid >> 4;
  int m0 = mt * 128, n0 = nt * 128;
  int tid = threadIdx.x;
  int lane = tid & 63, w = tid >> 6;
  int wr = w >> 1, wc = w & 1;
  int l15 = lane & 15, l4 = lane >> 4;

  f32x4 acc[4][4];
#pragma unroll
  for (int i = 0; i < 4; ++i)
#pragma unroll
    for (int j = 0; j < 4; ++j) acc[i][j] = (f32x4){0.f, 0.f, 0.f, 0.f};

  const short* arow[4];
#pragma unroll
  for (int fm = 0; fm < 4; ++fm)
    arow[fm] = A + (size_t)(m0 + wr * 64 + fm * 16 + l15) * KP_ + l4 * 8;

  auto stage = [&](int kc, int buf) {
    const short* gb = Bt + (size_t)n0 * KP_ + kc * 64;
#pragma unroll
    for (int i = 0; i < 4; ++i) {
      int ch = tid + i * 256;
      int rr = ch >> 3, kq = (ch & 7) * 8;
      gload_lds16(gb + (size_t)rr * KP_ + kq, &sB[buf][rr * 64 + kq]);
    }
  };

  stage(0, 0);
  __syncthreads();
  int buf = 0;
  for (int kc = 0; kc < 8; ++kc) {
    if (kc < 7) stage(kc + 1, buf ^ 1);
#pragma unroll
    for (int k2 = 0; k2 < 2; ++k2) {
      int kloc = k2 * 32 + l4 * 8;
      s16x8 af[4], bfr[4];
#pragma unroll
      for (int fm = 0; fm < 4; ++fm)
        af[fm] = *(const s16x8*)(arow[fm] + kc * 64 + k2 * 32);
#pragma unroll
      for (int fn = 0; fn < 4; ++fn)
        bfr[fn] = *(const s16x8*)&sB[buf][(wc * 64 + fn * 16 + l15) * 64 + kloc];
#pragma unroll
      for (int fm = 0; fm < 4; ++fm)
#pragma unroll
        for (int fn = 0; fn < 4; ++fn)
          acc[fm][fn] = __builtin_amdgcn_mfma_f32_16x16x32_bf16(af[fm], bfr[fn], acc[fm][fn], 0, 0, 0);
    }
    __syncthreads();
    buf ^= 1;
  }

  float bo4[4];
#pragma unroll
  for (int fn = 0; fn < 4; ++fn) bo4[fn] = bout[n0 + wc * 64 + fn * 16 + l15];

#pragma unroll
  for (int fm = 0; fm < 4; ++fm) {
#pragma unroll
    for (int reg = 0; reg < 4; ++reg) {
      int m = m0 + wr * 64 + fm * 16 + l4 * 4 + reg;
      float s = 0.f;
#pragma unroll
      for (int fn = 0; fn < 4; ++fn) {
        int n = n0 + wc * 64 + fn * 16 + l15;
        float e = __expf(acc[fm][fn][reg] + bo4[fn]);
        out[(size_t)m * V_ + n] = e;
        s += e;
      }
      s += __shfl_xor(s, 1);
      s += __shfl_xor(s, 2);
      s += __shfl_xor(s, 4);
      s += __shfl_xor(s, 8);
      if (l15 == 0) atomicAdd(&rowsum[m], s);
    }
  }
}

// ---------------- normalize: p = e / rowsum ----------------
__global__ __launch_bounds__(256) void k_norm(float* __restrict__ out,
                                              const float* __restrict__ rowsum) {
  size_t i = (size_t)blockIdx.x * 256 + threadIdx.x;  // f4 index; 16,384,000 total
  if (i >= 16384000ul) return;
  int row = (int)(i / 8000);
  float inv = 1.0f / rowsum[row];
  f32x4 v = *(f32x4*)(out + i * 4);
  v.x *= inv; v.y *= inv; v.z *= inv; v.w *= inv;
  *(f32x4*)(out + i * 4) = v;
}

extern "C" void kernel_launch(void* const* d_in, const int* in_sizes, int n_in,
                              void* d_out, int out_size, void* d_ws, size_t ws_size,
                              hipStream_t stream) {
  const float* img  = (const float*)d_in[0];
  const int*   cap  = (const int*)  d_in[1];
  const float* Wimg = (const float*)d_in[2];
  const float* bimg = (const float*)d_in[3];
  const float* emb  = (const float*)d_in[4];
  const float* Wl   = (const float*)d_in[5];
  const float* Ulm  = (const float*)d_in[6];
  const float* bl   = (const float*)d_in[7];
  const float* Wo   = (const float*)d_in[8];
  const float* bo   = (const float*)d_in[9];
  float* out = (float*)d_out;
  char* ws = (char*)d_ws;

  float* xz     = (float*)(ws + OFF_XZ);
  short* xb     = (short*)(ws + OFF_XB);
  short* wlt    = (short*)(ws + OFF_WLT);
  short* hpad   = (short*)(ws + OFF_HPAD);
  short* hs     = (short*)(ws + OFF_HS);
  short* uprep  = (short*)(ws + OFF_UPREP);
  short* wt     = (short*)(ws + OFF_WT);
  float* rowsum = (float*)(ws + OFF_RS);
  u32*   flags  = (u32*)d_out;               // d_out[0..32), zeroed by k_prep
  float* x32    = (float*)d_out + 1024;      // d_out scratch, overwritten later

  k_prep<<<SG_WLT, 256, 0, stream>>>(bimg, emb, cap, Ulm, Wl,
                                     xb, x32, rowsum, flags, uprep, wlt);
  k_img<<<128, 256, 0, stream>>>(img, Wimg, x32);
  k_xb<<<8, 256, 0, stream>>>(x32, xb);
  k_xzm<<<256, 256, 0, stream>>>(xb, wlt, bl, xz);

  {
    const short* up_p = uprep;
    const float* xz_p = xz;
    short* hpad_p = hpad;
    short* hs_p = hs;
    u32* flags_p = flags;
    const float* wo_p = Wo;
    short* wt_p = wt;
    void* args[] = {&up_p, &xz_p, &hpad_p, &hs_p, &flags_p, &wo_p, &wt_p};
    hipLaunchCooperativeKernel((void*)k_scan, dim3(256), dim3(128), args, 0, stream);
  }

  k_gemm<<<4000, 256, 0, stream>>>(hs, wt, bo, out, rowsum);
  k_norm<<<64000, 256, 0, stream>>>(out, rowsum);
}